// Round 2
// 980.936 us; speedup vs baseline: 2.1909x; 2.1909x over previous
//
#include <hip/hip_runtime.h>
#include <math.h>

#define N 150
#define NP 160            // padded: 4 workers × 40 cols, float4-aligned
#define QUART 40
#define QUADS 10          // QUART/4
#define BLOCK 640         // 10 waves; 4 workers per row (600 active)
#define ITERS 100
#define WARM 5
#define STEADY (ITERS - WARM - 1)   // fold does iteration 6 exactly; 94 remain

#define PI_F 3.14159265358979323846f
#define TWO_PI_F 6.28318530717958647692f
#define EPS_F 1e-16f
// SINKHORN_EPS = 0.05 ; base-2 log domain: K = C/(eps*ln2)
#define EPSLN2 0.03465735902799726f
#define INV_EPSLN2 28.853900817779268f
#define NEGBIG -1e30f

#if __has_builtin(__builtin_amdgcn_exp2f)
#define FEXP2(x) __builtin_amdgcn_exp2f(x)
#else
#define FEXP2(x) exp2f(x)
#endif
#if __has_builtin(__builtin_amdgcn_logf)
#define FLOG2(x) __builtin_amdgcn_logf(x)
#else
#define FLOG2(x) log2f(x)
#endif
#if __has_builtin(__builtin_amdgcn_rcpf)
#define FRCP(x) __builtin_amdgcn_rcpf(x)
#else
#define FRCP(x) (1.0f / (x))
#endif

__device__ __forceinline__ float blockReduceSum(float v, float* red) {
    for (int o = 32; o > 0; o >>= 1) v += __shfl_down(v, o, 64);
    const int lane = threadIdx.x & 63;
    const int wv = threadIdx.x >> 6;
    __syncthreads();
    if (lane == 0) red[wv] = v;
    __syncthreads();
    float s = 0.f;
    #pragma unroll
    for (int i = 0; i < BLOCK / 64; ++i) s += red[i];
    return s;
}

__global__ __launch_bounds__(BLOCK, 2) void emd_kernel(
    const float* __restrict__ p_recons,
    const float* __restrict__ p_target,
    float* __restrict__ out)
{
    __shared__ float xeta[N], xphi[N], yeta[N], yphi[N];
    __shared__ float l2a[N], l2b[N];
    __shared__ __align__(16) float uu[NP];
    __shared__ __align__(16) float vv[NP];
    __shared__ float red[BLOCK / 64];

    const int b = blockIdx.x;
    const int tid = threadIdx.x;

    // ---- coordinate transform (both clouds) ----
    for (int c = 0; c < 2; ++c) {
        const float* P = (c == 0 ? p_recons : p_target) + (size_t)b * (N * 3);
        float px = 0.f, py = 0.f, pz = 0.f;
        if (tid < N) {
            px = P[tid * 3 + 0];
            py = P[tid * 3 + 1];
            pz = P[tid * 3 + 2];
        }
        const float jx = blockReduceSum(px, red);
        const float jy = blockReduceSum(py, red);
        const float jz = blockReduceSum(pz, red);
        const float jpt  = sqrtf(jx * jx + jy * jy + EPS_F);
        const float jphi = atan2f(jy + EPS_F, jx + EPS_F);
        const float jeta = asinhf(jz / (jpt + EPS_F));

        float ptrel = 0.f, erel = 0.f, prel = 0.f;
        if (tid < N) {
            const float pt  = sqrtf(px * px + py * py + EPS_F);
            const float phi = atan2f(py + EPS_F, px + EPS_F);
            const float eta = asinhf(pz / (pt + EPS_F));
            erel = eta - jeta;
            float d = phi - jphi + PI_F;
            d = fmodf(d, TWO_PI_F);            // JAX % is floor-mod
            if (d < 0.f) d += TWO_PI_F;
            prel = d - PI_F;
            ptrel = pt / (jpt + EPS_F);
        }
        const float spt = blockReduceSum(ptrel, red);
        if (tid < N) {
            const float aa = ptrel / (spt + EPS_F);
            if (c == 0) { xeta[tid] = erel; xphi[tid] = prel; l2a[tid] = FLOG2(aa + EPS_F); }
            else        { yeta[tid] = erel; yphi[tid] = prel; l2b[tid] = FLOG2(aa + EPS_F); }
        }
    }
    __syncthreads();

    // ---- register-resident -K slices (log2 domain): 4 workers/row, 40 cols ----
    const int r = (tid >> 2) < N ? (tid >> 2) : (N - 1);   // clamped for uniform exec
    const int q = tid & 3;
    const bool writer = (q == 0) && ((tid >> 2) < N);
    const bool act = (tid >> 2) < N;

    float nKu[QUART];   // -K[r][q*40 + s]   (later: linear Ku' anchor)
    float nKt[QUART];   // -K[q*40 + s][r]   (later: linear Kt' anchor)
    {
        const float xe = xeta[r], xp = xphi[r];
        const float ye = yeta[r], yp = yphi[r];
        #pragma unroll
        for (int s = 0; s < QUART; ++s) {
            const int j = q * QUART + s;
            float ku = NEGBIG, kt = NEGBIG;       // pads never contribute
            if (j < N) {
                float de = xe - yeta[j], dp = xp - yphi[j];
                ku = -sqrtf(de * de + dp * dp + EPS_F) * INV_EPSLN2;
                de = xeta[j] - ye; dp = xphi[j] - yp;
                kt = -sqrtf(de * de + dp * dp + EPS_F) * INV_EPSLN2;
            }
            nKu[s] = ku;
            nKt[s] = kt;
        }
    }
    if (tid < NP) {
        const float z = (tid < N) ? 0.f : NEGBIG;   // pads stay NEGBIG in log phase
        uu[tid] = z; vv[tid] = z;
    }
    __syncthreads();

    // ---- warm-up: iterations 1..WARM, exact two-pass LSE in log2 domain ----
    for (int it = 0; it < WARM; ++it) {
        {   // u-pass
            const float4* vp = (const float4*)&vv[q * QUART];
            float mx = -3e38f;
            #pragma unroll
            for (int s = 0; s < QUADS; ++s) {
                const float4 v4 = vp[s];
                mx = fmaxf(mx, fmaxf(fmaxf(v4.x + nKu[4*s], v4.y + nKu[4*s+1]),
                                     fmaxf(v4.z + nKu[4*s+2], v4.w + nKu[4*s+3])));
            }
            mx = fmaxf(mx, __shfl_xor(mx, 1, 64));
            mx = fmaxf(mx, __shfl_xor(mx, 2, 64));
            float s0 = 0.f, s1 = 0.f, s2 = 0.f, s3 = 0.f;
            #pragma unroll
            for (int s = 0; s < QUADS; ++s) {
                const float4 v4 = vp[s];
                s0 += FEXP2(v4.x + nKu[4*s]   - mx);
                s1 += FEXP2(v4.y + nKu[4*s+1] - mx);
                s2 += FEXP2(v4.z + nKu[4*s+2] - mx);
                s3 += FEXP2(v4.w + nKu[4*s+3] - mx);
            }
            float ss = (s0 + s1) + (s2 + s3);
            ss += __shfl_xor(ss, 1, 64);
            ss += __shfl_xor(ss, 2, 64);
            if (writer) uu[r] = l2a[r] - (mx + FLOG2(fmaxf(ss, 1e-37f)));
        }
        __syncthreads();
        {   // v-pass
            const float4* up = (const float4*)&uu[q * QUART];
            float mx = -3e38f;
            #pragma unroll
            for (int s = 0; s < QUADS; ++s) {
                const float4 u4 = up[s];
                mx = fmaxf(mx, fmaxf(fmaxf(u4.x + nKt[4*s], u4.y + nKt[4*s+1]),
                                     fmaxf(u4.z + nKt[4*s+2], u4.w + nKt[4*s+3])));
            }
            mx = fmaxf(mx, __shfl_xor(mx, 1, 64));
            mx = fmaxf(mx, __shfl_xor(mx, 2, 64));
            float s0 = 0.f, s1 = 0.f, s2 = 0.f, s3 = 0.f;
            #pragma unroll
            for (int s = 0; s < QUADS; ++s) {
                const float4 u4 = up[s];
                s0 += FEXP2(u4.x + nKt[4*s]   - mx);
                s1 += FEXP2(u4.y + nKt[4*s+1] - mx);
                s2 += FEXP2(u4.z + nKt[4*s+2] - mx);
                s3 += FEXP2(u4.w + nKt[4*s+3] - mx);
            }
            float ss = (s0 + s1) + (s2 + s3);
            ss += __shfl_xor(ss, 1, 64);
            ss += __shfl_xor(ss, 2, 64);
            if (writer) vv[r] = l2b[r] - (mx + FLOG2(fmaxf(ss, 1e-37f)));
        }
        __syncthreads();
    }

    // ---- FOLD: iteration WARM+1 done exactly, building linear anchors ----
    //   Ku'[s] = exp2(nK + v5_j - mu_r), mu_r fresh  -> row max == 1
    //   am = ss6 (linear row sum), fin = a_r / ss6
    //   Kt'[s] = exp2(nK^T + u6_j - mv_c), mv_c fresh -> col max == 1
    //   bm = Vhat6 * ssv6 ; LDS switches to linear Uhat/Vhat
    float am, bm, fin, Vh6;
    {   // u-update (exact, fresh max) + Ku' anchor
        const float4* vp = (const float4*)&vv[q * QUART];
        float mx = -3e38f;
        #pragma unroll
        for (int s = 0; s < QUADS; ++s) {
            const float4 v4 = vp[s];
            mx = fmaxf(mx, fmaxf(fmaxf(v4.x + nKu[4*s], v4.y + nKu[4*s+1]),
                                 fmaxf(v4.z + nKu[4*s+2], v4.w + nKu[4*s+3])));
        }
        mx = fmaxf(mx, __shfl_xor(mx, 1, 64));
        mx = fmaxf(mx, __shfl_xor(mx, 2, 64));
        float s0 = 0.f, s1 = 0.f, s2 = 0.f, s3 = 0.f;
        #pragma unroll
        for (int s = 0; s < QUADS; ++s) {
            const float4 v4 = vp[s];
            nKu[4*s]   = FEXP2(v4.x + nKu[4*s]   - mx);
            nKu[4*s+1] = FEXP2(v4.y + nKu[4*s+1] - mx);
            nKu[4*s+2] = FEXP2(v4.z + nKu[4*s+2] - mx);
            nKu[4*s+3] = FEXP2(v4.w + nKu[4*s+3] - mx);
            s0 += nKu[4*s]; s1 += nKu[4*s+1]; s2 += nKu[4*s+2]; s3 += nKu[4*s+3];
        }
        float ss = (s0 + s1) + (s2 + s3);
        ss += __shfl_xor(ss, 1, 64);
        ss += __shfl_xor(ss, 2, 64);          // ss6 >= 1 (argmax term is exactly 1)
        am  = ss;                              // exp2(l2a - mu - u6) == ss6
        fin = FEXP2(l2a[r]) * FRCP(ss);        // exp2(u6 + mu) == a_r / ss6
        if (writer) uu[r] = l2a[r] - (mx + FLOG2(ss));   // u6 (log2, temporary)
    }
    __syncthreads();
    {   // v-update (exact) + Kt' anchor
        const float4* up = (const float4*)&uu[q * QUART];
        float mx = -3e38f;
        #pragma unroll
        for (int s = 0; s < QUADS; ++s) {
            const float4 u4 = up[s];
            mx = fmaxf(mx, fmaxf(fmaxf(u4.x + nKt[4*s], u4.y + nKt[4*s+1]),
                                 fmaxf(u4.z + nKt[4*s+2], u4.w + nKt[4*s+3])));
        }
        mx = fmaxf(mx, __shfl_xor(mx, 1, 64));
        mx = fmaxf(mx, __shfl_xor(mx, 2, 64));
        float s0 = 0.f, s1 = 0.f, s2 = 0.f, s3 = 0.f;
        #pragma unroll
        for (int s = 0; s < QUADS; ++s) {
            const float4 u4 = up[s];
            nKt[4*s]   = FEXP2(u4.x + nKt[4*s]   - mx);
            nKt[4*s+1] = FEXP2(u4.y + nKt[4*s+1] - mx);
            nKt[4*s+2] = FEXP2(u4.z + nKt[4*s+2] - mx);
            nKt[4*s+3] = FEXP2(u4.w + nKt[4*s+3] - mx);
            s0 += nKt[4*s]; s1 += nKt[4*s+1]; s2 += nKt[4*s+2]; s3 += nKt[4*s+3];
        }
        float ssv = (s0 + s1) + (s2 + s3);
        ssv += __shfl_xor(ssv, 1, 64);
        ssv += __shfl_xor(ssv, 2, 64);        // ssv6 >= 1
        const float v5r = vv[r];              // old (log) anchor of this column
        float t = l2b[r] - (mx + FLOG2(ssv)) - v5r;   // v6 - v5
        t = fminf(t, 100.f);                  // overflow guard (renorm re-anchors)
        Vh6 = FEXP2(t);
        bm  = Vh6 * ssv;                      // exp2(l2b - mv - v5)
    }
    __syncthreads();                          // all reads of uu (u6) / vv (v5) done
    if (writer) { uu[r] = 1.0f; vv[r] = Vh6; }
    if (tid >= N && tid < NP) { uu[tid] = 0.f; vv[tid] = 0.f; }  // pads: exact 0
    __syncthreads();

    // ---- steady state: iterations WARM+2 .. 100 in linear domain ----
    // one v_fmac per element; renorm every 8 iters bounds drift, exp2-free
    for (int it = 0; it < STEADY; ++it) {
        {   // u-pass: ss = Ku' . Vhat ; Uhat = am/ss
            const float4* vp = (const float4*)&vv[q * QUART];
            float s0 = 0.f, s1 = 0.f, s2 = 0.f, s3 = 0.f;
            #pragma unroll
            for (int s = 0; s < QUADS; ++s) {
                const float4 v4 = vp[s];
                s0 = fmaf(v4.x, nKu[4*s],   s0);
                s1 = fmaf(v4.y, nKu[4*s+1], s1);
                s2 = fmaf(v4.z, nKu[4*s+2], s2);
                s3 = fmaf(v4.w, nKu[4*s+3], s3);
            }
            float ss = (s0 + s1) + (s2 + s3);
            ss += __shfl_xor(ss, 1, 64);
            ss += __shfl_xor(ss, 2, 64);
            if (writer) uu[r] = fminf(am * FRCP(fmaxf(ss, 1e-30f)), 1e30f);
        }
        __syncthreads();
        {   // v-pass: ssv = Kt' . Uhat ; Vhat = bm/ssv
            const float4* up = (const float4*)&uu[q * QUART];
            float s0 = 0.f, s1 = 0.f, s2 = 0.f, s3 = 0.f;
            #pragma unroll
            for (int s = 0; s < QUADS; ++s) {
                const float4 u4 = up[s];
                s0 = fmaf(u4.x, nKt[4*s],   s0);
                s1 = fmaf(u4.y, nKt[4*s+1], s1);
                s2 = fmaf(u4.z, nKt[4*s+2], s2);
                s3 = fmaf(u4.w, nKt[4*s+3], s3);
            }
            float ss = (s0 + s1) + (s2 + s3);
            ss += __shfl_xor(ss, 1, 64);
            ss += __shfl_xor(ss, 2, 64);
            if (writer) vv[r] = fminf(bm * FRCP(fmaxf(ss, 1e-30f)), 1e30f);
        }
        __syncthreads();
        if ((it & 7) == 7) {
            // ---- renorm: fold Uhat/Vhat into anchors, reset to 1 (exp2-free) ----
            const float4* vp = (const float4*)&vv[q * QUART];
            float M = 0.f;
            #pragma unroll
            for (int s = 0; s < QUADS; ++s) {
                const float4 v4 = vp[s];
                nKu[4*s]   *= v4.x; nKu[4*s+1] *= v4.y;
                nKu[4*s+2] *= v4.z; nKu[4*s+3] *= v4.w;
                M = fmaxf(M, fmaxf(fmaxf(nKu[4*s], nKu[4*s+1]),
                                   fmaxf(nKu[4*s+2], nKu[4*s+3])));
            }
            M = fmaxf(M, __shfl_xor(M, 1, 64));
            M = fmaxf(M, __shfl_xor(M, 2, 64));
            M = fmaxf(M, 1e-30f);
            const float rM = FRCP(M);
            #pragma unroll
            for (int s = 0; s < QUART; ++s) nKu[s] *= rM;   // row max -> 1

            const float4* up = (const float4*)&uu[q * QUART];
            float Mv = 0.f;
            #pragma unroll
            for (int s = 0; s < QUADS; ++s) {
                const float4 u4 = up[s];
                nKt[4*s]   *= u4.x; nKt[4*s+1] *= u4.y;
                nKt[4*s+2] *= u4.z; nKt[4*s+3] *= u4.w;
                Mv = fmaxf(Mv, fmaxf(fmaxf(nKt[4*s], nKt[4*s+1]),
                                     fmaxf(nKt[4*s+2], nKt[4*s+3])));
            }
            Mv = fmaxf(Mv, __shfl_xor(Mv, 1, 64));
            Mv = fmaxf(Mv, __shfl_xor(Mv, 2, 64));
            Mv = fmaxf(Mv, 1e-30f);
            const float rMv = FRCP(Mv);
            #pragma unroll
            for (int s = 0; s < QUART; ++s) nKt[s] *= rMv;  // col max -> 1

            const float Uh = uu[r], Vh = vv[r];
            am  = fminf(am * rM  * FRCP(fmaxf(Uh, 1e-30f)), 1e30f);
            bm  = fminf(bm * rMv * FRCP(fmaxf(Vh, 1e-30f)), 1e30f);
            fin = fminf(fin * M * Uh, 1e30f);
            __syncthreads();                   // all folds read uu/vv
            if (writer) { uu[r] = 1.0f; vv[r] = 1.0f; }
            __syncthreads();
        }
    }

    // ---- EMD: exp2(u+v-K)*C = fin * Uhat[r] * Vhat[j] * Ku'[s] * C ----
    float acc = 0.f;
    if (act) {
        const float u2 = fin * uu[r];
        const float xe = xeta[r], xp = xphi[r];
        const float4* vp = (const float4*)&vv[q * QUART];
        #pragma unroll
        for (int s = 0; s < QUADS; ++s) {
            const float4 v4 = vp[s];
            const float vc[4] = { v4.x, v4.y, v4.z, v4.w };
            #pragma unroll
            for (int c2 = 0; c2 < 4; ++c2) {
                const int j = q * QUART + 4 * s + c2;
                if (j < N) {
                    const float de = xe - yeta[j];
                    const float dp = xp - yphi[j];
                    const float C = sqrtf(de * de + dp * dp + EPS_F);
                    acc += u2 * vc[c2] * nKu[4 * s + c2] * C;
                }
            }
        }
    }
    acc = blockReduceSum(acc, red);
    if (tid == 0) atomicAdd(out, acc);
}

extern "C" void kernel_launch(void* const* d_in, const int* in_sizes, int n_in,
                              void* d_out, int out_size, void* d_ws, size_t ws_size,
                              hipStream_t stream) {
    const float* pr = (const float*)d_in[0];
    const float* pt = (const float*)d_in[1];
    float* out = (float*)d_out;
    const int B = in_sizes[0] / (N * 3);
    hipMemsetAsync(d_out, 0, sizeof(float) * out_size, stream);
    hipLaunchKernelGGL(emd_kernel, dim3(B), dim3(BLOCK), 0, stream, pr, pt, out);
}